// Round 14
// baseline (135.592 us; speedup 1.0000x reference)
//
#include <hip/hip_runtime.h>
#include <hip/hip_bf16.h>

#define IN_CH 256
#define OUT_CH 128
#define BIN_SHIFT 6                 // 64 dst nodes per bin
#define BIN_SIZE 64
#define MAXNB2 2048                 // bin-count cap (need 1563)
#define CHUNK3 4096                 // k1/k3 edges per block
#define NBLK_MAX 512                // chunk-block cap (need 391)
#define K4BATCH 1536                // k4 records per batch
#define K4CAP 2048                  // k4 sorted capacity (1536 + 64*7 = 1984)

using bf16x8 = __attribute__((ext_vector_type(8))) __bf16;
using f32x16 = __attribute__((ext_vector_type(16))) float;
using f32x4  = __attribute__((ext_vector_type(4))) float;
using f32x2  = __attribute__((ext_vector_type(2))) float;

__device__ __forceinline__ unsigned int f2bf(float f) {
    union { float f; unsigned u; } v; v.f = f;
    unsigned r = v.u + 0x7fffu + ((v.u >> 16) & 1u);
    return r >> 16;
}

// ---------------- K1: fused prep_w (blocks 0..7) + per-block bin histogram ----------------
__global__ void __launch_bounds__(512) k1_hist(
    const float* __restrict__ W, unsigned short* __restrict__ Wfrag,
    const int* __restrict__ edge_dst, unsigned short* __restrict__ bh,
    int n_edges, int nb2) {
    const int t = threadIdx.x;
    if (blockIdx.x < 8) {
        // W (f32 [128][256]) -> bf16 MFMA B-fragment order; 4096 frag-groups total
        const int flat = blockIdx.x * 512 + t;
        const int l = flat & 63;
        const int ks = (flat >> 6) & 15;
        const int c = flat >> 10;
        const int row = c * 32 + (l & 31);
        const int col0 = ks * 16 + 8 * (l >> 5);
        const float* src = W + (size_t)row * IN_CH + col0;
        uint4 o;
        o.x = f2bf(src[0]) | (f2bf(src[1]) << 16);
        o.y = f2bf(src[2]) | (f2bf(src[3]) << 16);
        o.z = f2bf(src[4]) | (f2bf(src[5]) << 16);
        o.w = f2bf(src[6]) | (f2bf(src[7]) << 16);
        *reinterpret_cast<uint4*>(Wfrag + (size_t)flat * 8) = o;
        return;
    }
    __shared__ int hist[MAXNB2];
    const int blk = blockIdx.x - 8;
    for (int i = t; i < MAXNB2; i += 512) hist[i] = 0;
    __syncthreads();
    const int base = blk * CHUNK3;
#pragma unroll
    for (int j = 0; j < CHUNK3 / 512; ++j) {
        int e = base + j * 512 + t;
        if (e < n_edges) atomicAdd(&hist[edge_dst[e] >> BIN_SHIFT], 1);
    }
    __syncthreads();
    for (int i = t; i < nb2; i += 512) bh[(size_t)i * NBLK_MAX + blk] = (unsigned short)hist[i];
}

// ---------------- K2a: per-bin exclusive scan over chunk-blocks ----------------
__global__ void __launch_bounds__(512) k2a_scan_cols(
    const unsigned short* __restrict__ bh, unsigned short* __restrict__ offs,
    int* __restrict__ total, int nblk) {
    __shared__ int sd[512];
    const int t = threadIdx.x;
    const int bin = blockIdx.x;
    int val = (t < nblk) ? (int)bh[(size_t)bin * NBLK_MAX + t] : 0;
    sd[t] = val;
    __syncthreads();
    for (int s = 1; s < 512; s <<= 1) {
        int y = (t >= s) ? sd[t - s] : 0;
        __syncthreads();
        sd[t] += y;
        __syncthreads();
    }
    offs[(size_t)bin * NBLK_MAX + t] = (unsigned short)(sd[t] - val);
    if (t == 511) total[bin] = sd[511];
}

// ---------------- K2b: exclusive scan over bin totals -> base ----------------
__global__ void __launch_bounds__(512) k2b_scan_base(
    const int* __restrict__ total, int* __restrict__ base, int nb2) {
    __shared__ int sd[512];
    const int t = threadIdx.x;
    int v[4];
    int loc = 0;
#pragma unroll
    for (int k = 0; k < 4; ++k) {
        int idx = t * 4 + k;
        v[k] = (idx < nb2) ? total[idx] : 0;
        loc += v[k];
    }
    sd[t] = loc;
    __syncthreads();
    for (int s = 1; s < 512; s <<= 1) {
        int y = (t >= s) ? sd[t - s] : 0;
        __syncthreads();
        sd[t] += y;
        __syncthreads();
    }
    int run = sd[t] - loc;
#pragma unroll
    for (int k = 0; k < 4; ++k) {
        int idx = t * 4 + k;
        if (idx < nb2) base[idx] = run;
        run += v[k];
    }
    if (t == 511) base[nb2] = sd[511];
}

// ---------------- linear: h = bf16(x @ W.T + b); Wfrag staged in LDS ----------------
__global__ void __launch_bounds__(512) linear_mfma(
    const float* __restrict__ x, const unsigned short* __restrict__ Wfrag,
    const float* __restrict__ b, unsigned short* __restrict__ h, int n_nodes) {
    __shared__ uint4 wlds[4096];     // 64 KB: full Wfrag in fragment order
    const int tid = threadIdx.x;
    const int w = tid >> 6, l = tid & 63;
    const int l31 = l & 31, lh = l >> 5;
    const int node0 = blockIdx.x * 256 + w * 32;

    {
        const uint4* wfg = reinterpret_cast<const uint4*>(Wfrag);
#pragma unroll
        for (int j = 0; j < 8; ++j) wlds[j * 512 + tid] = wfg[j * 512 + tid];
    }
    __syncthreads();

    int arow = node0 + l31;
    if (arow > n_nodes - 1) arow = n_nodes - 1;
    const float* xrow = x + (size_t)arow * IN_CH + 8 * lh;

    f32x16 acc0 = {}, acc1 = {}, acc2 = {}, acc3 = {};

#pragma unroll 4
    for (int ks = 0; ks < 16; ++ks) {
        float4 a0 = *reinterpret_cast<const float4*>(xrow + ks * 16);
        float4 a1 = *reinterpret_cast<const float4*>(xrow + ks * 16 + 4);
        bf16x8 af;
        af[0] = (__bf16)a0.x; af[1] = (__bf16)a0.y;
        af[2] = (__bf16)a0.z; af[3] = (__bf16)a0.w;
        af[4] = (__bf16)a1.x; af[5] = (__bf16)a1.y;
        af[6] = (__bf16)a1.z; af[7] = (__bf16)a1.w;

        uint4 bw0 = wlds[(0 * 16 + ks) * 64 + l];
        uint4 bw1 = wlds[(1 * 16 + ks) * 64 + l];
        uint4 bw2 = wlds[(2 * 16 + ks) * 64 + l];
        uint4 bw3 = wlds[(3 * 16 + ks) * 64 + l];

        acc0 = __builtin_amdgcn_mfma_f32_32x32x16_bf16(af, __builtin_bit_cast(bf16x8, bw0), acc0, 0, 0, 0);
        acc1 = __builtin_amdgcn_mfma_f32_32x32x16_bf16(af, __builtin_bit_cast(bf16x8, bw1), acc1, 0, 0, 0);
        acc2 = __builtin_amdgcn_mfma_f32_32x32x16_bf16(af, __builtin_bit_cast(bf16x8, bw2), acc2, 0, 0, 0);
        acc3 = __builtin_amdgcn_mfma_f32_32x32x16_bf16(af, __builtin_bit_cast(bf16x8, bw3), acc3, 0, 0, 0);
    }

    const float bias0 = b[0 + l31], bias1 = b[32 + l31], bias2 = b[64 + l31], bias3 = b[96 + l31];
#pragma unroll
    for (int reg = 0; reg < 16; ++reg) {
        const int r = (reg & 3) + 8 * (reg >> 2) + 4 * lh;
        const int node = node0 + r;
        if (node < n_nodes) {
            unsigned short* hp = h + (size_t)node * OUT_CH;
            __bf16 t0 = (__bf16)(acc0[reg] + bias0);
            __bf16 t1 = (__bf16)(acc1[reg] + bias1);
            __bf16 t2 = (__bf16)(acc2[reg] + bias2);
            __bf16 t3 = (__bf16)(acc3[reg] + bias3);
            hp[0 + l31]  = __builtin_bit_cast(unsigned short, t0);
            hp[32 + l31] = __builtin_bit_cast(unsigned short, t1);
            hp[64 + l31] = __builtin_bit_cast(unsigned short, t2);
            hp[96 + l31] = __builtin_bit_cast(unsigned short, t3);
        }
    }
}

// ---------------- K3: chunk counting-sort by 64-dst bin, coalesced record write ---------
// record u64: [w_bf16:48-63 | bin:24-35 | dst&63:17-22 | src:0-16]
__global__ void __launch_bounds__(512) k3_bin(
    const int* __restrict__ edge_src, const int* __restrict__ edge_dst,
    const float* __restrict__ edge_weight,
    const unsigned short* __restrict__ offs, const int* __restrict__ base,
    unsigned long long* __restrict__ records, int n_edges, int nb2) {
    __shared__ unsigned long long staged[CHUNK3];   // 32 KB
    __shared__ int hist[MAXNB2];                    // 8 KB
    __shared__ int cur[MAXNB2];                     // 8 KB
    __shared__ int gbase[MAXNB2];                   // 8 KB
    __shared__ int sd[512];

    const int t = threadIdx.x;
    const int blk = blockIdx.x;
    const int ebase = blk * CHUNK3;
    const int count = min(CHUNK3, n_edges - ebase);

    for (int i = t; i < MAXNB2; i += 512) hist[i] = 0;
    __syncthreads();
#pragma unroll
    for (int j = 0; j < CHUNK3 / 512; ++j) {
        int e = ebase + j * 512 + t;
        if (e < n_edges) atomicAdd(&hist[edge_dst[e] >> BIN_SHIFT], 1);
    }
    __syncthreads();
    // exclusive scan of 2048 bins, 4 per thread
    int h0 = hist[4 * t], h1 = hist[4 * t + 1], h2 = hist[4 * t + 2], h3 = hist[4 * t + 3];
    int loc = h0 + h1 + h2 + h3;
    sd[t] = loc;
    __syncthreads();
    for (int s = 1; s < 512; s <<= 1) {
        int y = (t >= s) ? sd[t - s] : 0;
        __syncthreads();
        sd[t] += y;
        __syncthreads();
    }
    int excl = sd[t] - loc;
    {
        int run = excl;
        cur[4 * t] = run; run += h0;
        cur[4 * t + 1] = run; run += h1;
        cur[4 * t + 2] = run; run += h2;
        cur[4 * t + 3] = run;
    }
    {
        int run = excl;
#pragma unroll
        for (int k = 0; k < 4; ++k) {
            int bin = 4 * t + k;
            if (bin < nb2)
                gbase[bin] = base[bin] + (int)offs[(size_t)bin * NBLK_MAX + blk] - run;
            run += (k == 0 ? h0 : k == 1 ? h1 : k == 2 ? h2 : h3);
        }
    }
    __syncthreads();
#pragma unroll
    for (int j = 0; j < CHUNK3 / 512; ++j) {
        int e = ebase + j * 512 + t;
        if (e < n_edges) {
            int d = edge_dst[e];
            int bin = d >> BIN_SHIFT;
            unsigned int wbits = f2bf(edge_weight[e]);   // bf16 bits
            unsigned long long rec = ((unsigned long long)wbits << 48) |
                                     ((unsigned long long)bin << 24) |
                                     ((unsigned long long)(d & (BIN_SIZE - 1)) << 17) |
                                     (unsigned int)edge_src[e];
            int pos = atomicAdd(&cur[bin], 1);
            staged[pos] = rec;
        }
    }
    __syncthreads();
    for (int i = t; i < count; i += 512) {
        unsigned long long r = staged[i];
        int bin = (int)((r >> 24) & 4095u);
        records[gbase[bin] + i] = r;
    }
}

// ---------------- K4: per-bin dst-sort (8-padded) + scalarized 8-deep gather ----------
// grid = nb2; block owns 64 dsts. 256 threads = 4 waves; wave w owns 16 dst rows;
// lane owns channels 2l, 2l+1.
__global__ void __launch_bounds__(256) k4_agg(
    const unsigned short* __restrict__ h, const unsigned long long* __restrict__ records,
    const int* __restrict__ base, float* __restrict__ out, int n_nodes) {
    __shared__ unsigned long long sorted[K4CAP];   // 16 KB
    __shared__ int hist[BIN_SIZE];
    __shared__ int cur[BIN_SIZE];
    __shared__ int pstart[BIN_SIZE];
    __shared__ int sd[BIN_SIZE];
    __shared__ int ptot;

    const int t = threadIdx.x;
    const int bin = blockIdx.x;
    const int w = t >> 6, lane = t & 63;
    const int rbeg = base[bin], rend = base[bin + 1];

    float acc[16][2];
#pragma unroll
    for (int d = 0; d < 16; ++d) { acc[d][0] = 0.f; acc[d][1] = 0.f; }

    for (int b0 = rbeg; b0 < rend; b0 += K4BATCH) {
        const int cnt = min(K4BATCH, rend - b0);
        __syncthreads();  // previous batch fully consumed
        if (t < BIN_SIZE) hist[t] = 0;
        __syncthreads();
        // histogram by dst-low (coalesced read of own segment)
        for (int i = t; i < cnt; i += 256)
            atomicAdd(&hist[(unsigned)(records[b0 + i] >> 17) & 63u], 1);
        __syncthreads();
        // exclusive scan of ceil8(hist) over 64 bins
        if (t < BIN_SIZE) sd[t] = (hist[t] + 7) & ~7;
        __syncthreads();
        for (int s = 1; s < BIN_SIZE; s <<= 1) {
            int y = 0;
            if (t < BIN_SIZE && t >= s) y = sd[t - s];
            __syncthreads();
            if (t < BIN_SIZE) sd[t] += y;
            __syncthreads();
        }
        if (t < BIN_SIZE) {
            const int e = sd[t] - ((hist[t] + 7) & ~7);
            pstart[t] = e;
            cur[t] = e;
        }
        if (t == BIN_SIZE - 1) ptot = sd[BIN_SIZE - 1];
        __syncthreads();
        // zero padded region (pad records: w=0, src=0 -> contribute nothing)
        const int pt = ptot;
        for (int i = t; i < pt; i += 256) sorted[i] = 0ull;
        __syncthreads();
        // scatter into dst-sorted order
        for (int i = t; i < cnt; i += 256) {
            const unsigned long long r = records[b0 + i];
            const int dl = (int)((unsigned)(r >> 17) & 63u);
            const int pos = atomicAdd(&cur[dl], 1);
            sorted[pos] = r;
        }
        __syncthreads();
        // aggregate: wave w handles dl = w*16+d; 8-padded segments, branchless G=8
#pragma unroll
        for (int d = 0; d < 16; ++d) {
            const int dl = w * 16 + d;
            const int s0 = pstart[dl];
            const int s1 = s0 + hist[dl];
            float a0 = 0.f, a1 = 0.f;
            for (int i = s0; i < s1; i += 8) {
                unsigned int hv[8];
                float wt[8];
#pragma unroll
                for (int j = 0; j < 8; ++j) {
                    const unsigned long long rr = sorted[i + j];   // uniform broadcast
                    const unsigned lo = __builtin_amdgcn_readfirstlane((unsigned)rr);
                    const unsigned hi = __builtin_amdgcn_readfirstlane((unsigned)(rr >> 32));
                    wt[j] = __builtin_bit_cast(float, hi & 0xFFFF0000u);
                    const unsigned* hp = reinterpret_cast<const unsigned*>(
                        h + (size_t)(lo & 0x1FFFFu) * OUT_CH);
                    hv[j] = hp[lane];   // global_load_dword v, v_off, s[base]
                }
#pragma unroll
                for (int j = 0; j < 8; ++j) {
                    a0 += wt[j] * __builtin_bit_cast(float, hv[j] << 16);
                    a1 += wt[j] * __builtin_bit_cast(float, hv[j] & 0xFFFF0000u);
                }
            }
            acc[d][0] += a0;
            acc[d][1] += a1;
        }
    }

    // write out: coalesced 8B per lane per dst row
#pragma unroll
    for (int d = 0; d < 16; ++d) {
        const int node = bin * BIN_SIZE + w * 16 + d;
        if (node < n_nodes) {
            f32x2 v = {acc[d][0], acc[d][1]};
            __builtin_nontemporal_store(
                v, reinterpret_cast<f32x2*>(out + (size_t)node * OUT_CH + 2 * lane));
        }
    }
}

extern "C" void kernel_launch(void* const* d_in, const int* in_sizes, int n_in,
                              void* d_out, int out_size, void* d_ws, size_t ws_size,
                              hipStream_t stream) {
    const float* x           = (const float*)d_in[0];
    const int*   edge_src    = (const int*)d_in[1];
    const int*   edge_dst    = (const int*)d_in[2];
    const float* edge_weight = (const float*)d_in[3];
    const float* W           = (const float*)d_in[4];
    const float* b           = (const float*)d_in[5];
    float* out = (float*)d_out;

    const int n_nodes = in_sizes[0] / IN_CH;
    const int n_edges = in_sizes[1];
    const int nb2 = (n_nodes + BIN_SIZE - 1) / BIN_SIZE;         // 1563
    const int nblk = (n_edges + CHUNK3 - 1) / CHUNK3;            // 391

    // workspace layout
    unsigned long long* records = (unsigned long long*)d_ws;            // E * 8B
    unsigned short* h     = (unsigned short*)(records + n_edges);       // N*128 bf16
    unsigned short* bh    = (unsigned short*)(h + (size_t)n_nodes * OUT_CH); // 2048*512 u16
    unsigned short* offs  = bh + (size_t)MAXNB2 * NBLK_MAX;             // 2048*512 u16
    int* total = (int*)(offs + (size_t)MAXNB2 * NBLK_MAX);              // 2048
    int* base  = total + MAXNB2;                                        // 2048+1
    unsigned short* Wfrag = (unsigned short*)(base + MAXNB2 + 2);       // 64 KB

    k1_hist<<<8 + nblk, 512, 0, stream>>>(W, Wfrag, edge_dst, bh, n_edges, nb2);
    k2a_scan_cols<<<nb2, 512, 0, stream>>>(bh, offs, total, nblk);
    k2b_scan_base<<<1, 512, 0, stream>>>(total, base, nb2);
    linear_mfma<<<(n_nodes + 255) / 256, 512, 0, stream>>>(x, Wfrag, b, h, n_nodes);
    k3_bin<<<nblk, 512, 0, stream>>>(edge_src, edge_dst, edge_weight,
                                     offs, base, records, n_edges, nb2);
    k4_agg<<<nb2, 256, 0, stream>>>(h, records, base, out, n_nodes);
}

// Round 15
// 131.281 us; speedup vs baseline: 1.0328x; 1.0328x over previous
//
#include <hip/hip_runtime.h>
#include <hip/hip_bf16.h>

#define IN_CH 256
#define OUT_CH 128
#define BIN_SHIFT 6                 // 64 dst nodes per bin
#define BIN_SIZE 64
#define MAXNB2 2048                 // bin-count cap (need 1563)
#define CHUNK3 4096                 // k1/k3 edges per block
#define NBLK_MAX 512                // chunk-block cap (need 391)
#define K4BATCH 1536                // k4 records per batch
#define K4CAP 2048                  // k4 sorted capacity (1536 + 64*7 = 1984)

using bf16x8 = __attribute__((ext_vector_type(8))) __bf16;
using f32x16 = __attribute__((ext_vector_type(16))) float;
using f32x4  = __attribute__((ext_vector_type(4))) float;
using f32x2  = __attribute__((ext_vector_type(2))) float;

__device__ __forceinline__ unsigned int f2bf(float f) {
    union { float f; unsigned u; } v; v.f = f;
    unsigned r = v.u + 0x7fffu + ((v.u >> 16) & 1u);
    return r >> 16;
}

// ---------------- K1: fused prep_w (blocks 0..7) + per-block bin histogram ----------------
__global__ void __launch_bounds__(512) k1_hist(
    const float* __restrict__ W, unsigned short* __restrict__ Wfrag,
    const int* __restrict__ edge_dst, unsigned short* __restrict__ bh,
    int n_edges, int nb2) {
    const int t = threadIdx.x;
    if (blockIdx.x < 8) {
        const int flat = blockIdx.x * 512 + t;
        const int l = flat & 63;
        const int ks = (flat >> 6) & 15;
        const int c = flat >> 10;
        const int row = c * 32 + (l & 31);
        const int col0 = ks * 16 + 8 * (l >> 5);
        const float* src = W + (size_t)row * IN_CH + col0;
        uint4 o;
        o.x = f2bf(src[0]) | (f2bf(src[1]) << 16);
        o.y = f2bf(src[2]) | (f2bf(src[3]) << 16);
        o.z = f2bf(src[4]) | (f2bf(src[5]) << 16);
        o.w = f2bf(src[6]) | (f2bf(src[7]) << 16);
        *reinterpret_cast<uint4*>(Wfrag + (size_t)flat * 8) = o;
        return;
    }
    __shared__ int hist[MAXNB2];
    const int blk = blockIdx.x - 8;
    for (int i = t; i < MAXNB2; i += 512) hist[i] = 0;
    __syncthreads();
    const int base = blk * CHUNK3;
#pragma unroll
    for (int j = 0; j < CHUNK3 / 512; ++j) {
        int e = base + j * 512 + t;
        if (e < n_edges) atomicAdd(&hist[edge_dst[e] >> BIN_SHIFT], 1);
    }
    __syncthreads();
    for (int i = t; i < nb2; i += 512) bh[(size_t)i * NBLK_MAX + blk] = (unsigned short)hist[i];
}

// ---------------- K2a: per-bin exclusive scan over chunk-blocks ----------------
__global__ void __launch_bounds__(512) k2a_scan_cols(
    const unsigned short* __restrict__ bh, unsigned short* __restrict__ offs,
    int* __restrict__ total, int nblk) {
    __shared__ int sd[512];
    const int t = threadIdx.x;
    const int bin = blockIdx.x;
    int val = (t < nblk) ? (int)bh[(size_t)bin * NBLK_MAX + t] : 0;
    sd[t] = val;
    __syncthreads();
    for (int s = 1; s < 512; s <<= 1) {
        int y = (t >= s) ? sd[t - s] : 0;
        __syncthreads();
        sd[t] += y;
        __syncthreads();
    }
    offs[(size_t)bin * NBLK_MAX + t] = (unsigned short)(sd[t] - val);
    if (t == 511) total[bin] = sd[511];
}

// ---------------- K2b: exclusive scan over bin totals -> base ----------------
__global__ void __launch_bounds__(512) k2b_scan_base(
    const int* __restrict__ total, int* __restrict__ base, int nb2) {
    __shared__ int sd[512];
    const int t = threadIdx.x;
    int v[4];
    int loc = 0;
#pragma unroll
    for (int k = 0; k < 4; ++k) {
        int idx = t * 4 + k;
        v[k] = (idx < nb2) ? total[idx] : 0;
        loc += v[k];
    }
    sd[t] = loc;
    __syncthreads();
    for (int s = 1; s < 512; s <<= 1) {
        int y = (t >= s) ? sd[t - s] : 0;
        __syncthreads();
        sd[t] += y;
        __syncthreads();
    }
    int run = sd[t] - loc;
#pragma unroll
    for (int k = 0; k < 4; ++k) {
        int idx = t * 4 + k;
        if (idx < nb2) base[idx] = run;
        run += v[k];
    }
    if (t == 511) base[nb2] = sd[511];
}

// ---------------- K3+linear fused: blocks [0,nblk) sort edges; rest do MFMA ----------
// k3 record u64: [w_bf16:48-63 | bin:24-35 | dst&63:17-22 | src:0-16]
__global__ void __launch_bounds__(512) k3_linear(
    const int* __restrict__ edge_src, const int* __restrict__ edge_dst,
    const float* __restrict__ edge_weight,
    const unsigned short* __restrict__ offs, const int* __restrict__ base,
    unsigned long long* __restrict__ records, int n_edges, int nb2, int nblk,
    const float* __restrict__ x, const unsigned short* __restrict__ Wfrag,
    const float* __restrict__ b, unsigned short* __restrict__ h, int n_nodes) {
    __shared__ __align__(16) char smem[65536];
    const int t = threadIdx.x;

    if ((int)blockIdx.x < nblk) {
        // ================= k3: chunk counting-sort by 64-dst bin =================
        unsigned long long* staged = (unsigned long long*)smem;        // 32 KB
        int* hist  = (int*)(smem + 32768);                             // 8 KB
        int* cur   = (int*)(smem + 40960);                             // 8 KB
        int* gbase = (int*)(smem + 49152);                             // 8 KB
        int* sd    = (int*)(smem + 57344);                             // 2 KB

        const int blk = blockIdx.x;
        const int ebase = blk * CHUNK3;
        const int count = min(CHUNK3, n_edges - ebase);

        for (int i = t; i < MAXNB2; i += 512) hist[i] = 0;
        __syncthreads();
#pragma unroll
        for (int j = 0; j < CHUNK3 / 512; ++j) {
            int e = ebase + j * 512 + t;
            if (e < n_edges) atomicAdd(&hist[edge_dst[e] >> BIN_SHIFT], 1);
        }
        __syncthreads();
        int h0 = hist[4 * t], h1 = hist[4 * t + 1], h2 = hist[4 * t + 2], h3 = hist[4 * t + 3];
        int loc = h0 + h1 + h2 + h3;
        sd[t] = loc;
        __syncthreads();
        for (int s = 1; s < 512; s <<= 1) {
            int y = (t >= s) ? sd[t - s] : 0;
            __syncthreads();
            sd[t] += y;
            __syncthreads();
        }
        int excl = sd[t] - loc;
        {
            int run = excl;
            cur[4 * t] = run; run += h0;
            cur[4 * t + 1] = run; run += h1;
            cur[4 * t + 2] = run; run += h2;
            cur[4 * t + 3] = run;
        }
        {
            int run = excl;
#pragma unroll
            for (int k = 0; k < 4; ++k) {
                int bin = 4 * t + k;
                if (bin < nb2)
                    gbase[bin] = base[bin] + (int)offs[(size_t)bin * NBLK_MAX + blk] - run;
                run += (k == 0 ? h0 : k == 1 ? h1 : k == 2 ? h2 : h3);
            }
        }
        __syncthreads();
#pragma unroll
        for (int j = 0; j < CHUNK3 / 512; ++j) {
            int e = ebase + j * 512 + t;
            if (e < n_edges) {
                int d = edge_dst[e];
                int bin = d >> BIN_SHIFT;
                unsigned int wbits = f2bf(edge_weight[e]);
                unsigned long long rec = ((unsigned long long)wbits << 48) |
                                         ((unsigned long long)bin << 24) |
                                         ((unsigned long long)(d & (BIN_SIZE - 1)) << 17) |
                                         (unsigned int)edge_src[e];
                int pos = atomicAdd(&cur[bin], 1);
                staged[pos] = rec;
            }
        }
        __syncthreads();
        for (int i = t; i < count; i += 512) {
            unsigned long long r = staged[i];
            int bin = (int)((r >> 24) & 4095u);
            records[gbase[bin] + i] = r;
        }
        return;
    }

    // ================= linear: h = bf16(x @ W.T + b), Wfrag in LDS =================
    uint4* wlds = (uint4*)smem;   // 64 KB
    const int w = t >> 6, l = t & 63;
    const int l31 = l & 31, lh = l >> 5;
    const int node0 = (blockIdx.x - nblk) * 256 + w * 32;

    {
        const uint4* wfg = reinterpret_cast<const uint4*>(Wfrag);
#pragma unroll
        for (int j = 0; j < 8; ++j) wlds[j * 512 + t] = wfg[j * 512 + t];
    }
    __syncthreads();

    int arow = node0 + l31;
    if (arow > n_nodes - 1) arow = n_nodes - 1;
    const float* xrow = x + (size_t)arow * IN_CH + 8 * lh;

    f32x16 acc0 = {}, acc1 = {}, acc2 = {}, acc3 = {};

#pragma unroll 4
    for (int ks = 0; ks < 16; ++ks) {
        float4 a0 = *reinterpret_cast<const float4*>(xrow + ks * 16);
        float4 a1 = *reinterpret_cast<const float4*>(xrow + ks * 16 + 4);
        bf16x8 af;
        af[0] = (__bf16)a0.x; af[1] = (__bf16)a0.y;
        af[2] = (__bf16)a0.z; af[3] = (__bf16)a0.w;
        af[4] = (__bf16)a1.x; af[5] = (__bf16)a1.y;
        af[6] = (__bf16)a1.z; af[7] = (__bf16)a1.w;

        uint4 bw0 = wlds[(0 * 16 + ks) * 64 + l];
        uint4 bw1 = wlds[(1 * 16 + ks) * 64 + l];
        uint4 bw2 = wlds[(2 * 16 + ks) * 64 + l];
        uint4 bw3 = wlds[(3 * 16 + ks) * 64 + l];

        acc0 = __builtin_amdgcn_mfma_f32_32x32x16_bf16(af, __builtin_bit_cast(bf16x8, bw0), acc0, 0, 0, 0);
        acc1 = __builtin_amdgcn_mfma_f32_32x32x16_bf16(af, __builtin_bit_cast(bf16x8, bw1), acc1, 0, 0, 0);
        acc2 = __builtin_amdgcn_mfma_f32_32x32x16_bf16(af, __builtin_bit_cast(bf16x8, bw2), acc2, 0, 0, 0);
        acc3 = __builtin_amdgcn_mfma_f32_32x32x16_bf16(af, __builtin_bit_cast(bf16x8, bw3), acc3, 0, 0, 0);
    }

    const float bias0 = b[0 + l31], bias1 = b[32 + l31], bias2 = b[64 + l31], bias3 = b[96 + l31];
#pragma unroll
    for (int reg = 0; reg < 16; ++reg) {
        const int r = (reg & 3) + 8 * (reg >> 2) + 4 * lh;
        const int node = node0 + r;
        if (node < n_nodes) {
            unsigned short* hp = h + (size_t)node * OUT_CH;
            __bf16 t0 = (__bf16)(acc0[reg] + bias0);
            __bf16 t1 = (__bf16)(acc1[reg] + bias1);
            __bf16 t2 = (__bf16)(acc2[reg] + bias2);
            __bf16 t3 = (__bf16)(acc3[reg] + bias3);
            hp[0 + l31]  = __builtin_bit_cast(unsigned short, t0);
            hp[32 + l31] = __builtin_bit_cast(unsigned short, t1);
            hp[64 + l31] = __builtin_bit_cast(unsigned short, t2);
            hp[96 + l31] = __builtin_bit_cast(unsigned short, t3);
        }
    }
}

// ---------------- K4: per-bin dst-sort (8-padded) + scalarized 8-deep gather ----------
// grid = nb2; block owns 64 dsts. 256 threads = 4 waves; wave w owns 16 dst rows;
// lane owns channels 2l, 2l+1. Records staged in LDS (one global read).
__global__ void __launch_bounds__(256) k4_agg(
    const unsigned short* __restrict__ h, const unsigned long long* __restrict__ records,
    const int* __restrict__ base, float* __restrict__ out, int n_nodes) {
    __shared__ unsigned long long sorted[K4CAP];    // 16 KB
    __shared__ unsigned long long staged[K4BATCH];  // 12 KB
    __shared__ int hist[BIN_SIZE];
    __shared__ int cur[BIN_SIZE];
    __shared__ int pstart[BIN_SIZE];
    __shared__ int sd[BIN_SIZE];
    __shared__ int ptot;

    const int t = threadIdx.x;
    const int bin = blockIdx.x;
    const int w = t >> 6, lane = t & 63;
    const int rbeg = base[bin], rend = base[bin + 1];

    float acc[16][2];
#pragma unroll
    for (int d = 0; d < 16; ++d) { acc[d][0] = 0.f; acc[d][1] = 0.f; }

    for (int b0 = rbeg; b0 < rend; b0 += K4BATCH) {
        const int cnt = min(K4BATCH, rend - b0);
        __syncthreads();  // previous batch fully consumed
        // stage records into LDS (coalesced; the ONLY global read of the segment)
        for (int i = t; i < cnt; i += 256) staged[i] = records[b0 + i];
        if (t < BIN_SIZE) hist[t] = 0;
        __syncthreads();
        // histogram by dst-low
        for (int i = t; i < cnt; i += 256)
            atomicAdd(&hist[(unsigned)(staged[i] >> 17) & 63u], 1);
        __syncthreads();
        // exclusive scan of ceil8(hist) over 64 bins
        if (t < BIN_SIZE) sd[t] = (hist[t] + 7) & ~7;
        __syncthreads();
        for (int s = 1; s < BIN_SIZE; s <<= 1) {
            int y = 0;
            if (t < BIN_SIZE && t >= s) y = sd[t - s];
            __syncthreads();
            if (t < BIN_SIZE) sd[t] += y;
            __syncthreads();
        }
        if (t < BIN_SIZE) {
            const int e = sd[t] - ((hist[t] + 7) & ~7);
            pstart[t] = e;
            cur[t] = e;
        }
        if (t == BIN_SIZE - 1) ptot = sd[BIN_SIZE - 1];
        __syncthreads();
        // zero padded region (pad records: w=0, src=0 -> contribute nothing)
        const int pt = ptot;
        for (int i = t; i < pt; i += 256) sorted[i] = 0ull;
        __syncthreads();
        // scatter into dst-sorted order
        for (int i = t; i < cnt; i += 256) {
            const unsigned long long r = staged[i];
            const int dl = (int)((unsigned)(r >> 17) & 63u);
            const int pos = atomicAdd(&cur[dl], 1);
            sorted[pos] = r;
        }
        __syncthreads();
        // aggregate: wave w handles dl = w*16+d; 8-padded segments, branchless G=8
#pragma unroll
        for (int d = 0; d < 16; ++d) {
            const int dl = w * 16 + d;
            const int s0 = pstart[dl];
            const int s1 = s0 + hist[dl];
            float a0 = 0.f, a1 = 0.f;
            for (int i = s0; i < s1; i += 8) {
                unsigned int hv[8];
                float wt[8];
#pragma unroll
                for (int j = 0; j < 8; ++j) {
                    const unsigned long long rr = sorted[i + j];   // uniform broadcast
                    const unsigned lo = __builtin_amdgcn_readfirstlane((unsigned)rr);
                    const unsigned hi = __builtin_amdgcn_readfirstlane((unsigned)(rr >> 32));
                    wt[j] = __builtin_bit_cast(float, hi & 0xFFFF0000u);
                    const unsigned* hp = reinterpret_cast<const unsigned*>(
                        h + (size_t)(lo & 0x1FFFFu) * OUT_CH);
                    hv[j] = hp[lane];   // global_load_dword v, v_off, s[base]
                }
#pragma unroll
                for (int j = 0; j < 8; ++j) {
                    a0 += wt[j] * __builtin_bit_cast(float, hv[j] << 16);
                    a1 += wt[j] * __builtin_bit_cast(float, hv[j] & 0xFFFF0000u);
                }
            }
            acc[d][0] += a0;
            acc[d][1] += a1;
        }
    }

    // write out: coalesced 8B per lane per dst row
#pragma unroll
    for (int d = 0; d < 16; ++d) {
        const int node = bin * BIN_SIZE + w * 16 + d;
        if (node < n_nodes) {
            f32x2 v = {acc[d][0], acc[d][1]};
            __builtin_nontemporal_store(
                v, reinterpret_cast<f32x2*>(out + (size_t)node * OUT_CH + 2 * lane));
        }
    }
}

extern "C" void kernel_launch(void* const* d_in, const int* in_sizes, int n_in,
                              void* d_out, int out_size, void* d_ws, size_t ws_size,
                              hipStream_t stream) {
    const float* x           = (const float*)d_in[0];
    const int*   edge_src    = (const int*)d_in[1];
    const int*   edge_dst    = (const int*)d_in[2];
    const float* edge_weight = (const float*)d_in[3];
    const float* W           = (const float*)d_in[4];
    const float* b           = (const float*)d_in[5];
    float* out = (float*)d_out;

    const int n_nodes = in_sizes[0] / IN_CH;
    const int n_edges = in_sizes[1];
    const int nb2 = (n_nodes + BIN_SIZE - 1) / BIN_SIZE;         // 1563
    const int nblk = (n_edges + CHUNK3 - 1) / CHUNK3;            // 391
    const int lblocks = (n_nodes + 255) / 256;                   // 391

    // workspace layout
    unsigned long long* records = (unsigned long long*)d_ws;            // E * 8B
    unsigned short* h     = (unsigned short*)(records + n_edges);       // N*128 bf16
    unsigned short* bh    = (unsigned short*)(h + (size_t)n_nodes * OUT_CH); // 2048*512 u16
    unsigned short* offs  = bh + (size_t)MAXNB2 * NBLK_MAX;             // 2048*512 u16
    int* total = (int*)(offs + (size_t)MAXNB2 * NBLK_MAX);              // 2048
    int* base  = total + MAXNB2;                                        // 2048+1
    unsigned short* Wfrag = (unsigned short*)(base + MAXNB2 + 2);       // 64 KB

    k1_hist<<<8 + nblk, 512, 0, stream>>>(W, Wfrag, edge_dst, bh, n_edges, nb2);
    k2a_scan_cols<<<nb2, 512, 0, stream>>>(bh, offs, total, nblk);
    k2b_scan_base<<<1, 512, 0, stream>>>(total, base, nb2);
    k3_linear<<<nblk + lblocks, 512, 0, stream>>>(
        edge_src, edge_dst, edge_weight, offs, base, records, n_edges, nb2, nblk,
        x, Wfrag, b, h, n_nodes);
    k4_agg<<<nb2, 256, 0, stream>>>(h, records, base, out, n_nodes);
}

// Round 16
// 131.128 us; speedup vs baseline: 1.0340x; 1.0012x over previous
//
#include <hip/hip_runtime.h>
#include <hip/hip_bf16.h>

#define IN_CH 256
#define OUT_CH 128
#define BIN_SHIFT 6                 // 64 dst nodes per bin
#define BIN_SIZE 64
#define MAXNB2 2048                 // bin-count cap (need 1563)
#define CHUNK3 4096                 // hist/k3 edges per block
#define NBLK_MAX 512                // chunk-block cap (need 391)
#define K4BATCH 1536                // k4 records per batch
#define K4CAP 2048                  // k4 sorted capacity (1536 + 64*7 = 1984)

using bf16x8 = __attribute__((ext_vector_type(8))) __bf16;
using f32x16 = __attribute__((ext_vector_type(16))) float;
using f32x4  = __attribute__((ext_vector_type(4))) float;
using f32x2  = __attribute__((ext_vector_type(2))) float;

__device__ __forceinline__ unsigned int f2bf(float f) {
    union { float f; unsigned u; } v; v.f = f;
    unsigned r = v.u + 0x7fffu + ((v.u >> 16) & 1u);
    return r >> 16;
}

// ---------------- D1: fused linear (blocks [0,lblocks)) + bin histogram ----------------
// linear: h = bf16(x @ W.T + b); W converted to fragment order inline (no prep pass).
__global__ void __launch_bounds__(512) k1_linear(
    const float* __restrict__ W, const int* __restrict__ edge_dst,
    unsigned short* __restrict__ bh, int n_edges, int nb2,
    const float* __restrict__ x, const float* __restrict__ b,
    unsigned short* __restrict__ h, int n_nodes, int lblocks) {
    __shared__ __align__(16) char smem[65536];
    const int t = threadIdx.x;

    if ((int)blockIdx.x < lblocks) {
        // ============ linear ============
        uint4* wlds = (uint4*)smem;   // 64 KB Wfrag in fragment order
        const int w = t >> 6, l = t & 63;
        const int l31 = l & 31, lh = l >> 5;
        const int node0 = blockIdx.x * 256 + w * 32;

        // stage W -> LDS fragment order with inline f32->bf16 conversion
#pragma unroll
        for (int j = 0; j < 8; ++j) {
            const int flat = j * 512 + t;          // 0..4095
            const int fl = flat & 63;
            const int ks = (flat >> 6) & 15;
            const int c = flat >> 10;
            const int row = c * 32 + (fl & 31);
            const int col0 = ks * 16 + 8 * (fl >> 5);
            const float* src = W + (size_t)row * IN_CH + col0;
            float4 s0 = *reinterpret_cast<const float4*>(src);
            float4 s1 = *reinterpret_cast<const float4*>(src + 4);
            uint4 o;
            o.x = f2bf(s0.x) | (f2bf(s0.y) << 16);
            o.y = f2bf(s0.z) | (f2bf(s0.w) << 16);
            o.z = f2bf(s1.x) | (f2bf(s1.y) << 16);
            o.w = f2bf(s1.z) | (f2bf(s1.w) << 16);
            wlds[flat] = o;
        }
        __syncthreads();

        int arow = node0 + l31;
        if (arow > n_nodes - 1) arow = n_nodes - 1;
        const float* xrow = x + (size_t)arow * IN_CH + 8 * lh;

        f32x16 acc0 = {}, acc1 = {}, acc2 = {}, acc3 = {};

#pragma unroll 4
        for (int ks = 0; ks < 16; ++ks) {
            float4 a0 = *reinterpret_cast<const float4*>(xrow + ks * 16);
            float4 a1 = *reinterpret_cast<const float4*>(xrow + ks * 16 + 4);
            bf16x8 af;
            af[0] = (__bf16)a0.x; af[1] = (__bf16)a0.y;
            af[2] = (__bf16)a0.z; af[3] = (__bf16)a0.w;
            af[4] = (__bf16)a1.x; af[5] = (__bf16)a1.y;
            af[6] = (__bf16)a1.z; af[7] = (__bf16)a1.w;

            uint4 bw0 = wlds[(0 * 16 + ks) * 64 + l];
            uint4 bw1 = wlds[(1 * 16 + ks) * 64 + l];
            uint4 bw2 = wlds[(2 * 16 + ks) * 64 + l];
            uint4 bw3 = wlds[(3 * 16 + ks) * 64 + l];

            acc0 = __builtin_amdgcn_mfma_f32_32x32x16_bf16(af, __builtin_bit_cast(bf16x8, bw0), acc0, 0, 0, 0);
            acc1 = __builtin_amdgcn_mfma_f32_32x32x16_bf16(af, __builtin_bit_cast(bf16x8, bw1), acc1, 0, 0, 0);
            acc2 = __builtin_amdgcn_mfma_f32_32x32x16_bf16(af, __builtin_bit_cast(bf16x8, bw2), acc2, 0, 0, 0);
            acc3 = __builtin_amdgcn_mfma_f32_32x32x16_bf16(af, __builtin_bit_cast(bf16x8, bw3), acc3, 0, 0, 0);
        }

        const float bias0 = b[0 + l31], bias1 = b[32 + l31], bias2 = b[64 + l31], bias3 = b[96 + l31];
#pragma unroll
        for (int reg = 0; reg < 16; ++reg) {
            const int r = (reg & 3) + 8 * (reg >> 2) + 4 * lh;
            const int node = node0 + r;
            if (node < n_nodes) {
                unsigned short* hp = h + (size_t)node * OUT_CH;
                __bf16 t0 = (__bf16)(acc0[reg] + bias0);
                __bf16 t1 = (__bf16)(acc1[reg] + bias1);
                __bf16 t2 = (__bf16)(acc2[reg] + bias2);
                __bf16 t3 = (__bf16)(acc3[reg] + bias3);
                hp[0 + l31]  = __builtin_bit_cast(unsigned short, t0);
                hp[32 + l31] = __builtin_bit_cast(unsigned short, t1);
                hp[64 + l31] = __builtin_bit_cast(unsigned short, t2);
                hp[96 + l31] = __builtin_bit_cast(unsigned short, t3);
            }
        }
        return;
    }

    // ============ per-block bin histogram ============
    int* hist = (int*)smem;   // 8 KB
    const int blk = blockIdx.x - lblocks;
    for (int i = t; i < MAXNB2; i += 512) hist[i] = 0;
    __syncthreads();
    const int base = blk * CHUNK3;
#pragma unroll
    for (int j = 0; j < CHUNK3 / 512; ++j) {
        int e = base + j * 512 + t;
        if (e < n_edges) atomicAdd(&hist[edge_dst[e] >> BIN_SHIFT], 1);
    }
    __syncthreads();
    for (int i = t; i < nb2; i += 512) bh[(size_t)i * NBLK_MAX + blk] = (unsigned short)hist[i];
}

// ---------------- K2a: per-bin exclusive scan over chunk-blocks ----------------
__global__ void __launch_bounds__(512) k2a_scan_cols(
    const unsigned short* __restrict__ bh, unsigned short* __restrict__ offs,
    int* __restrict__ total, int nblk) {
    __shared__ int sd[512];
    const int t = threadIdx.x;
    const int bin = blockIdx.x;
    int val = (t < nblk) ? (int)bh[(size_t)bin * NBLK_MAX + t] : 0;
    sd[t] = val;
    __syncthreads();
    for (int s = 1; s < 512; s <<= 1) {
        int y = (t >= s) ? sd[t - s] : 0;
        __syncthreads();
        sd[t] += y;
        __syncthreads();
    }
    offs[(size_t)bin * NBLK_MAX + t] = (unsigned short)(sd[t] - val);
    if (t == 511) total[bin] = sd[511];
}

// ---------------- K2b: exclusive scan over bin totals -> base ----------------
__global__ void __launch_bounds__(512) k2b_scan_base(
    const int* __restrict__ total, int* __restrict__ base, int nb2) {
    __shared__ int sd[512];
    const int t = threadIdx.x;
    int v[4];
    int loc = 0;
#pragma unroll
    for (int k = 0; k < 4; ++k) {
        int idx = t * 4 + k;
        v[k] = (idx < nb2) ? total[idx] : 0;
        loc += v[k];
    }
    sd[t] = loc;
    __syncthreads();
    for (int s = 1; s < 512; s <<= 1) {
        int y = (t >= s) ? sd[t - s] : 0;
        __syncthreads();
        sd[t] += y;
        __syncthreads();
    }
    int run = sd[t] - loc;
#pragma unroll
    for (int k = 0; k < 4; ++k) {
        int idx = t * 4 + k;
        if (idx < nb2) base[idx] = run;
        run += v[k];
    }
    if (t == 511) base[nb2] = sd[511];
}

// ---------------- K3: chunk counting-sort by 64-dst bin, coalesced record write ---------
// record u64: [w_bf16:48-63 | bin:24-35 | dst&63:17-22 | src:0-16]
__global__ void __launch_bounds__(512) k3_bin(
    const int* __restrict__ edge_src, const int* __restrict__ edge_dst,
    const float* __restrict__ edge_weight,
    const unsigned short* __restrict__ offs, const int* __restrict__ base,
    unsigned long long* __restrict__ records, int n_edges, int nb2) {
    __shared__ unsigned long long staged[CHUNK3];   // 32 KB
    __shared__ int hist[MAXNB2];                    // 8 KB
    __shared__ int cur[MAXNB2];                     // 8 KB
    __shared__ int gbase[MAXNB2];                   // 8 KB
    __shared__ int sd[512];

    const int t = threadIdx.x;
    const int blk = blockIdx.x;
    const int ebase = blk * CHUNK3;
    const int count = min(CHUNK3, n_edges - ebase);

    for (int i = t; i < MAXNB2; i += 512) hist[i] = 0;
    __syncthreads();
#pragma unroll
    for (int j = 0; j < CHUNK3 / 512; ++j) {
        int e = ebase + j * 512 + t;
        if (e < n_edges) atomicAdd(&hist[edge_dst[e] >> BIN_SHIFT], 1);
    }
    __syncthreads();
    int h0 = hist[4 * t], h1 = hist[4 * t + 1], h2 = hist[4 * t + 2], h3 = hist[4 * t + 3];
    int loc = h0 + h1 + h2 + h3;
    sd[t] = loc;
    __syncthreads();
    for (int s = 1; s < 512; s <<= 1) {
        int y = (t >= s) ? sd[t - s] : 0;
        __syncthreads();
        sd[t] += y;
        __syncthreads();
    }
    int excl = sd[t] - loc;
    {
        int run = excl;
        cur[4 * t] = run; run += h0;
        cur[4 * t + 1] = run; run += h1;
        cur[4 * t + 2] = run; run += h2;
        cur[4 * t + 3] = run;
    }
    {
        int run = excl;
#pragma unroll
        for (int k = 0; k < 4; ++k) {
            int bin = 4 * t + k;
            if (bin < nb2)
                gbase[bin] = base[bin] + (int)offs[(size_t)bin * NBLK_MAX + blk] - run;
            run += (k == 0 ? h0 : k == 1 ? h1 : k == 2 ? h2 : h3);
        }
    }
    __syncthreads();
#pragma unroll
    for (int j = 0; j < CHUNK3 / 512; ++j) {
        int e = ebase + j * 512 + t;
        if (e < n_edges) {
            int d = edge_dst[e];
            int bin = d >> BIN_SHIFT;
            unsigned int wbits = f2bf(edge_weight[e]);
            unsigned long long rec = ((unsigned long long)wbits << 48) |
                                     ((unsigned long long)bin << 24) |
                                     ((unsigned long long)(d & (BIN_SIZE - 1)) << 17) |
                                     (unsigned int)edge_src[e];
            int pos = atomicAdd(&cur[bin], 1);
            staged[pos] = rec;
        }
    }
    __syncthreads();
    for (int i = t; i < count; i += 512) {
        unsigned long long r = staged[i];
        int bin = (int)((r >> 24) & 4095u);
        records[gbase[bin] + i] = r;
    }
}

// ---------------- K4: per-bin dst-sort (8-padded, wave-scan) + scalarized gather -------
// grid = nb2; block owns 64 dsts. 256 threads = 4 waves; wave w owns 16 dst rows;
// lane owns channels 2l, 2l+1.
__global__ void __launch_bounds__(256) k4_agg(
    const unsigned short* __restrict__ h, const unsigned long long* __restrict__ records,
    const int* __restrict__ base, float* __restrict__ out, int n_nodes) {
    __shared__ unsigned long long sorted[K4CAP];    // 16 KB
    __shared__ unsigned long long staged[K4BATCH];  // 12 KB
    __shared__ int hist[BIN_SIZE];
    __shared__ int cur[BIN_SIZE];
    __shared__ int pstart[BIN_SIZE];
    __shared__ int ptot;

    const int t = threadIdx.x;
    const int bin = blockIdx.x;
    const int w = t >> 6, lane = t & 63;
    const int rbeg = base[bin], rend = base[bin + 1];

    float acc[16][2];
#pragma unroll
    for (int d = 0; d < 16; ++d) { acc[d][0] = 0.f; acc[d][1] = 0.f; }

    for (int b0 = rbeg; b0 < rend; b0 += K4BATCH) {
        const int cnt = min(K4BATCH, rend - b0);
        __syncthreads();  // previous batch fully consumed
        // stage records into LDS (coalesced)
        for (int i = t; i < cnt; i += 256) staged[i] = records[b0 + i];
        if (t < BIN_SIZE) hist[t] = 0;
        __syncthreads();
        // histogram by dst-low
        for (int i = t; i < cnt; i += 256)
            atomicAdd(&hist[(unsigned)(staged[i] >> 17) & 63u], 1);
        __syncthreads();
        // wave-0 shuffle scan of ceil8(hist) over 64 bins (no block barriers inside)
        if (t < BIN_SIZE) {
            const int v = (hist[t] + 7) & ~7;
            int s = v;
#pragma unroll
            for (int st = 1; st < 64; st <<= 1) {
                int y = __shfl_up(s, st);
                if (t >= st) s += y;
            }
            pstart[t] = s - v;
            cur[t] = s - v;
            if (t == 63) ptot = s;
        }
        __syncthreads();
        // zero padded region (pad records: w=0, src=0 -> contribute nothing)
        const int pt = ptot;
        for (int i = t; i < pt; i += 256) sorted[i] = 0ull;
        __syncthreads();
        // scatter into dst-sorted order
        for (int i = t; i < cnt; i += 256) {
            const unsigned long long r = staged[i];
            const int dl = (int)((unsigned)(r >> 17) & 63u);
            const int pos = atomicAdd(&cur[dl], 1);
            sorted[pos] = r;
        }
        __syncthreads();
        // aggregate: wave w handles dl = w*16+d; 8-padded segments, branchless G=8
#pragma unroll
        for (int d = 0; d < 16; ++d) {
            const int dl = w * 16 + d;
            const int s0 = pstart[dl];
            const int s1 = s0 + hist[dl];
            float a0 = 0.f, a1 = 0.f;
            for (int i = s0; i < s1; i += 8) {
                unsigned int hv[8];
                float wt[8];
#pragma unroll
                for (int j = 0; j < 8; ++j) {
                    const unsigned long long rr = sorted[i + j];   // uniform broadcast
                    const unsigned lo = __builtin_amdgcn_readfirstlane((unsigned)rr);
                    const unsigned hi = __builtin_amdgcn_readfirstlane((unsigned)(rr >> 32));
                    wt[j] = __builtin_bit_cast(float, hi & 0xFFFF0000u);
                    const unsigned* hp = reinterpret_cast<const unsigned*>(
                        h + (size_t)(lo & 0x1FFFFu) * OUT_CH);
                    hv[j] = hp[lane];   // global_load_dword v, v_off, s[base]
                }
#pragma unroll
                for (int j = 0; j < 8; ++j) {
                    a0 += wt[j] * __builtin_bit_cast(float, hv[j] << 16);
                    a1 += wt[j] * __builtin_bit_cast(float, hv[j] & 0xFFFF0000u);
                }
            }
            acc[d][0] += a0;
            acc[d][1] += a1;
        }
    }

    // write out: coalesced 8B per lane per dst row
#pragma unroll
    for (int d = 0; d < 16; ++d) {
        const int node = bin * BIN_SIZE + w * 16 + d;
        if (node < n_nodes) {
            f32x2 v = {acc[d][0], acc[d][1]};
            __builtin_nontemporal_store(
                v, reinterpret_cast<f32x2*>(out + (size_t)node * OUT_CH + 2 * lane));
        }
    }
}

extern "C" void kernel_launch(void* const* d_in, const int* in_sizes, int n_in,
                              void* d_out, int out_size, void* d_ws, size_t ws_size,
                              hipStream_t stream) {
    const float* x           = (const float*)d_in[0];
    const int*   edge_src    = (const int*)d_in[1];
    const int*   edge_dst    = (const int*)d_in[2];
    const float* edge_weight = (const float*)d_in[3];
    const float* W           = (const float*)d_in[4];
    const float* b           = (const float*)d_in[5];
    float* out = (float*)d_out;

    const int n_nodes = in_sizes[0] / IN_CH;
    const int n_edges = in_sizes[1];
    const int nb2 = (n_nodes + BIN_SIZE - 1) / BIN_SIZE;         // 1563
    const int nblk = (n_edges + CHUNK3 - 1) / CHUNK3;            // 391
    const int lblocks = (n_nodes + 255) / 256;                   // 391

    // workspace layout
    unsigned long long* records = (unsigned long long*)d_ws;            // E * 8B
    unsigned short* h     = (unsigned short*)(records + n_edges);       // N*128 bf16
    unsigned short* bh    = (unsigned short*)(h + (size_t)n_nodes * OUT_CH); // 2048*512 u16
    unsigned short* offs  = bh + (size_t)MAXNB2 * NBLK_MAX;             // 2048*512 u16
    int* total = (int*)(offs + (size_t)MAXNB2 * NBLK_MAX);              // 2048
    int* base  = total + MAXNB2;                                        // 2048+1

    // D1: linear (MFMA, HBM-streaming) overlapped with bin histogram
    k1_linear<<<lblocks + nblk, 512, 0, stream>>>(
        W, edge_dst, bh, n_edges, nb2, x, b, h, n_nodes, lblocks);
    // D2-D3: offset scans
    k2a_scan_cols<<<nb2, 512, 0, stream>>>(bh, offs, total, nblk);
    k2b_scan_base<<<1, 512, 0, stream>>>(total, base, nb2);
    // D4: counting-sort into bin-grouped records
    k3_bin<<<nblk, 512, 0, stream>>>(edge_src, edge_dst, edge_weight,
                                     offs, base, records, n_edges, nb2);
    // D5: per-bin aggregation
    k4_agg<<<nb2, 256, 0, stream>>>(h, records, base, out, n_nodes);
}